// Round 5
// baseline (549.910 us; speedup 1.0000x reference)
//
#include <hip/hip_runtime.h>
#include <math.h>

// Problem constants
#define NB    2048
#define NITER 15
#define MITER 3
#define IEPS  20.0f   // 1/0.05

typedef __bf16 bf16_t;
typedef bf16_t bf16x8 __attribute__((ext_vector_type(8)));
typedef bf16_t bf16x4 __attribute__((ext_vector_type(4)));
typedef float  f32x16 __attribute__((ext_vector_type(16)));

#define CSTR 65    // f32 elems per LDS C/T row (64 + 1 pad)

// W workspace layout (fragment-native):
//   wf[layer*65536 + ((eb*16 + kc)*64 + lane)*8 + u]
//   = W[eb*32 + (lane&31)][kc*16 + (lane>>5)*8 + u]

__global__ __launch_bounds__(256) void convert_w_frag(const float* __restrict__ W1,
                                                      const float* __restrict__ W2,
                                                      bf16_t* __restrict__ wf) {
    const int j19 = blockIdx.x * 256 + threadIdx.x;   // grid 512 -> 131072
    const int layer = j19 >> 16;
    const int j = j19 & 65535;
    const int u    = j & 7;
    const int lane = (j >> 3) & 63;
    const int kc   = (j >> 9) & 15;
    const int eb   = j >> 13;
    const int l31  = lane & 31;
    const int lh   = lane >> 5;
    const int src  = (eb * 32 + l31) * 256 + kc * 16 + lh * 8 + u;
    wf[j19] = (bf16_t)(layer ? W2[src] : W1[src]);
}

// ---------------------------------------------------------------------------
// Kernel A: persistent 256 blocks x 8 batches. X staged fp32 via
// global_load_lds (async DMA, zero VGPR cost) in 4 K-chunks of 64 into a
// 2-slot LDS buffer; chunk c+1 streams while chunk c is consumed (the
// __syncthreads vmcnt-drain overlaps the compute phase). L1 MFMA converts
// fp32->bf16 on LDS read. All tiles use a 16B-unit XOR swizzle
// phys_unit = unit ^ (row & 15)  (conflict-free: residual 2-way is free).
// DMA global source addresses are pre-swizzled so the LDS dest stays linear.
// LDS = 64K (X) + 64K (H/f) + 2.5K -> 1 block/CU; launch_bounds(512,2)
// gives a 256-VGPR budget: cross-phase state cannot spill (round-3 lesson).
// ---------------------------------------------------------------------------
__global__ __launch_bounds__(512, 2) void mlp_cdist(
    const float* __restrict__ sq, const float* __restrict__ sr,
    const float* __restrict__ b1, const float* __restrict__ b2,
    const bf16_t* __restrict__ wf,
    float* __restrict__ out) {

    __shared__ __align__(16) float  Xd[2][128 * 64];   // 2 x 32 KB fp32 K-chunks
    __shared__ __align__(16) bf16_t Hf[128 * 256];     // 64 KB H then f (swizzled)
    __shared__ float b1_s[256], b2_s[256];
    __shared__ float nrm[128];

    const int t   = threadIdx.x;
    const int ln  = t & 63;
    const int wv  = t >> 6;          // 0..7
    const int l31 = ln & 31;
    const int lh  = ln >> 5;
    const int sk  = l31 & 15;        // read-side swizzle key (== row&15 everywhere)

    if (t < 256) b1_s[t] = b1[t];
    else         b2_s[t - 256] = b2[t - 256];

    // ---- async DMA of one 32-KB fp32 K-chunk: wave wv covers rows 16wv..16wv+15
    auto issue_chunk = [&](int b, int c, int slot) {
        const float* base = (wv < 4) ? sq : sr;
        #pragma unroll
        for (int i = 0; i < 4; ++i) {
            const int R    = wv * 16 + i * 4 + (ln >> 4);      // 0..127
            const int Radj = (wv < 4) ? R : R - 64;
            const int u    = ln & 15;
            // source col-block pre-swizzled so linear LDS == swizzled layout
            const float* g = base + (size_t)b * 16384 + (size_t)Radj * 256
                           + c * 64 + ((u ^ (R & 15)) << 2);
            float* l = &Xd[slot][(wv * 4 + i) * 256];          // wave-uniform base
            __builtin_amdgcn_global_load_lds(
                (const __attribute__((address_space(1))) void*)g,
                (__attribute__((address_space(3))) void*)l, 16, 0, 0);
        }
    };

    // ---- L1 MFMA over one K-chunk (fp32 LDS read + cvt to bf16) ----
    auto l1_chunk = [&](int c, int slot, f32x16 acc[2][2]) {
        const bf16_t* wb = wf + ((size_t)(wv * 16 + c * 4)) * 512 + ln * 8;
        bf16x8 af[4];
        #pragma unroll
        for (int u = 0; u < 4; ++u) af[u] = *(const bf16x8*)(wb + (size_t)u * 512);
        const float* Xc = &Xd[slot][0];
        #pragma unroll
        for (int half = 0; half < 2; ++half) {
            const float* x0 = Xc + (half * 64 + l31) * 64;
            const float* x1 = x0 + 32 * 64;
            #pragma unroll
            for (int u = 0; u < 4; ++u) {
                const int p  = u * 4 + lh * 2;
                const int o0 = ((p ^ sk) << 2);
                const int o1 = (((p + 1) ^ sk) << 2);
                float4 a0 = *(const float4*)(x0 + o0);
                float4 a1 = *(const float4*)(x0 + o1);
                float4 c0 = *(const float4*)(x1 + o0);
                float4 c1 = *(const float4*)(x1 + o1);
                bf16x8 bx0, bx1;
                bx0[0]=(bf16_t)a0.x; bx0[1]=(bf16_t)a0.y; bx0[2]=(bf16_t)a0.z; bx0[3]=(bf16_t)a0.w;
                bx0[4]=(bf16_t)a1.x; bx0[5]=(bf16_t)a1.y; bx0[6]=(bf16_t)a1.z; bx0[7]=(bf16_t)a1.w;
                bx1[0]=(bf16_t)c0.x; bx1[1]=(bf16_t)c0.y; bx1[2]=(bf16_t)c0.z; bx1[3]=(bf16_t)c0.w;
                bx1[4]=(bf16_t)c1.x; bx1[5]=(bf16_t)c1.y; bx1[6]=(bf16_t)c1.z; bx1[7]=(bf16_t)c1.w;
                acc[half][0] = __builtin_amdgcn_mfma_f32_32x32x16_bf16(af[u], bx0, acc[half][0], 0, 0, 0);
                acc[half][1] = __builtin_amdgcn_mfma_f32_32x32x16_bf16(af[u], bx1, acc[half][1], 0, 0, 0);
            }
        }
    };

    int b = blockIdx.x * 8;
    issue_chunk(b, 0, 0);
    issue_chunk(b, 1, 1);

    for (int bi = 0; bi < 8; ++bi, ++b) {
        __syncthreads();                 // drains c0/c1 DMA; prev cdist done
        if (t < 128) nrm[t] = 0.0f;

        f32x16 acc[2][2];
        #pragma unroll
        for (int i = 0; i < 16; ++i) {
            acc[0][0][i] = 0.0f; acc[0][1][i] = 0.0f;
            acc[1][0][i] = 0.0f; acc[1][1][i] = 0.0f;
        }

        l1_chunk(0, 0, acc);
        __syncthreads();                 // slot0 consumed
        issue_chunk(b, 2, 0);
        l1_chunk(1, 1, acc);
        __syncthreads();                 // drains c2; slot1 consumed
        issue_chunk(b, 3, 1);
        l1_chunk(2, 0, acc);
        __syncthreads();                 // drains c3; slot0 consumed
        if (bi < 7) issue_chunk(b + 1, 0, 0);
        l1_chunk(3, 1, acc);

        // ---- L1 epilogue: bias + relu -> hreg (bf16) ----
        bf16x4 hreg[2][2][4];
        const int e0 = wv * 32;
        #pragma unroll
        for (int half = 0; half < 2; ++half)
            #pragma unroll
            for (int z = 0; z < 2; ++z)
                #pragma unroll
                for (int g = 0; g < 4; ++g) {
                    const int e = e0 + 8 * g + 4 * lh;
                    #pragma unroll
                    for (int rr = 0; rr < 4; ++rr)
                        hreg[half][z][g][rr] =
                            (bf16_t)fmaxf(acc[half][z][4 * g + rr] + b1_s[e + rr], 0.0f);
                }
        __syncthreads();                 // drains nc0; slot1 consumed

        // ---- write H -> Hf (unit-swizzled) ----
        #pragma unroll
        for (int half = 0; half < 2; ++half)
            #pragma unroll
            for (int z = 0; z < 2; ++z) {
                const int n = half * 64 + z * 32 + l31;        // n&15 == sk
                #pragma unroll
                for (int g = 0; g < 4; ++g) {
                    const int U = (wv * 4 + g) ^ sk;
                    *(bf16x4*)&Hf[n * 256 + U * 8 + 4 * lh] = hreg[half][z][g];
                }
            }
        __syncthreads();                 // H visible

        // ---- L2 + fused row norms ----
        {
            f32x16 acc2[2][2];
            #pragma unroll
            for (int i = 0; i < 16; ++i) {
                acc2[0][0][i] = 0.0f; acc2[0][1][i] = 0.0f;
                acc2[1][0][i] = 0.0f; acc2[1][1][i] = 0.0f;
            }
            #pragma unroll
            for (int kg = 0; kg < 2; ++kg) {
                const bf16_t* wb = wf + 65536 + ((size_t)(wv * 16 + kg * 8)) * 512 + ln * 8;
                bf16x8 af[8];
                #pragma unroll
                for (int u = 0; u < 8; ++u) af[u] = *(const bf16x8*)(wb + (size_t)u * 512);
                #pragma unroll
                for (int half = 0; half < 2; ++half) {
                    const bf16_t* h0 = Hf + (half * 64 + l31) * 256;
                    const bf16_t* h1 = h0 + 32 * 256;
                    #pragma unroll
                    for (int u = 0; u < 8; ++u) {
                        const int kc = kg * 8 + u;
                        const int pp = (((kc * 2 + lh) ^ sk) << 3);
                        bf16x8 bx0 = *(const bf16x8*)(h0 + pp);
                        bf16x8 bx1 = *(const bf16x8*)(h1 + pp);
                        acc2[half][0] = __builtin_amdgcn_mfma_f32_32x32x16_bf16(af[u], bx0, acc2[half][0], 0, 0, 0);
                        acc2[half][1] = __builtin_amdgcn_mfma_f32_32x32x16_bf16(af[u], bx1, acc2[half][1], 0, 0, 0);
                    }
                }
            }
            float ps[2][2] = {{0.0f, 0.0f}, {0.0f, 0.0f}};
            #pragma unroll
            for (int half = 0; half < 2; ++half)
                #pragma unroll
                for (int z = 0; z < 2; ++z)
                    #pragma unroll
                    for (int g = 0; g < 4; ++g) {
                        const int e = e0 + 8 * g + 4 * lh;
                        #pragma unroll
                        for (int rr = 0; rr < 4; ++rr) {
                            bf16_t bv = (bf16_t)(acc2[half][z][4 * g + rr] + b2_s[e + rr]);
                            hreg[half][z][g][rr] = bv;
                            float fv = (float)bv;
                            ps[half][z] = fmaf(fv, fv, ps[half][z]);
                        }
                    }
            #pragma unroll
            for (int half = 0; half < 2; ++half)
                #pragma unroll
                for (int z = 0; z < 2; ++z) {
                    float s = ps[half][z];
                    s += __shfl_xor(s, 32);
                    if (lh == 0) atomicAdd(&nrm[half * 64 + z * 32 + l31], s);
                }
        }
        __syncthreads();                 // all H reads done; nrm complete

        // ---- write f -> Hf (same swizzle) ----
        #pragma unroll
        for (int half = 0; half < 2; ++half)
            #pragma unroll
            for (int z = 0; z < 2; ++z) {
                const int n = half * 64 + z * 32 + l31;
                #pragma unroll
                for (int g = 0; g < 4; ++g) {
                    const int U = (wv * 4 + g) ^ sk;
                    *(bf16x4*)&Hf[n * 256 + U * 8 + 4 * lh] = hreg[half][z][g];
                }
            }
        __syncthreads();                 // f + nrm visible
        if (bi < 7) issue_chunk(b + 1, 1, 1);   // streams under cdist + next drain

        // ---- cdist (waves 0..3) -> C global ----
        if (wv < 4) {
            const int qt = wv >> 1, rt = wv & 1;
            const bf16_t* qa = Hf + (qt * 32 + l31) * 256;
            const bf16_t* ra = Hf + (64 + rt * 32 + l31) * 256;
            f32x16 accc;
            #pragma unroll
            for (int i = 0; i < 16; ++i) accc[i] = 0.0f;
            #pragma unroll
            for (int kc = 0; kc < 16; ++kc) {
                const int pp = (((kc * 2 + lh) ^ sk) << 3);
                bf16x8 av = *(const bf16x8*)(qa + pp);
                bf16x8 bv = *(const bf16x8*)(ra + pp);
                accc = __builtin_amdgcn_mfma_f32_32x32x16_bf16(av, bv, accc, 0, 0, 0);
            }
            const int mcol  = rt * 32 + l31;
            const int qbase = qt * 32;
            const float nr_m = nrm[64 + mcol];
            float* outC = out + 2048 + (size_t)2048 * 4096 + (size_t)b * 4096;
            #pragma unroll
            for (int g = 0; g < 4; ++g) {
                #pragma unroll
                for (int rr = 0; rr < 4; ++rr) {
                    const int q = qbase + 8 * g + 4 * lh + rr;
                    float d2 = nrm[q] + nr_m - 2.0f * accc[4 * g + rr];
                    outC[q * 64 + mcol] = sqrtf(fmaxf(d2, 0.0f));
                }
            }
        }
    }
}

// ---------------------------------------------------------------------------
// Kernel B: Sinkhorn + power iterations + outputs, from C in global.
// (Round-2 version, proven: 4 blocks/CU, full occupancy. Round-4's
//  zero-barrier wave-local variant was ~9 us slower -- chain length x TLP
//  beats barrier elimination here.)
// ---------------------------------------------------------------------------
__global__ __launch_bounds__(512, 8) void sinkhorn_from_C(
    const float* __restrict__ mq, const float* __restrict__ mr,
    float* __restrict__ out) {

    __shared__ float Cs[64 * CSTR];
    __shared__ float Ts[64 * CSTR];
    __shared__ float lmq_s[64], lmr_s[64], la_s[64], lb_s[64];
    __shared__ float red_s[8];

    const int b  = blockIdx.x;
    const int t  = threadIdx.x;
    const int ln = t & 63;
    const int wv = t >> 6;
    const int ki = t >> 3;      // 0..63 (row)
    const int jj = t & 7;       // strip of 8 cols

    const float* Cg = out + 2048 + (size_t)2048 * 4096 + (size_t)b * 4096 + ki * 64 + jj * 8;
    const float4 c0 = ((const float4*)Cg)[0];
    const float4 c1 = ((const float4*)Cg)[1];

    if (t < 64)        lmq_s[t]       = __logf(fmaxf(mq[(size_t)b * 64 + t], 1e-8f));
    else if (t < 128)  lmr_s[t - 64]  = __logf(fmaxf(mr[(size_t)b * 64 + (t - 64)], 1e-8f));
    else if (t < 192)  lb_s[t - 128]  = 0.0f;

    {
        float* cr = &Cs[ki * CSTR + jj * 8];
        cr[0] = c0.x; cr[1] = c0.y; cr[2] = c0.z; cr[3] = c0.w;
        cr[4] = c1.x; cr[5] = c1.y; cr[6] = c1.z; cr[7] = c1.w;
    }
    __syncthreads();

    float rowV[8], colV[8];
    {
        const float cv[8] = {c0.x, c0.y, c0.z, c0.w, c1.x, c1.y, c1.z, c1.w};
        #pragma unroll
        for (int i = 0; i < 8; ++i)
            rowV[i] = fmaf(cv[i], -IEPS, lmr_s[jj * 8 + i]);
        #pragma unroll
        for (int i = 0; i < 8; ++i)
            colV[i] = fmaf(Cs[(jj * 8 + i) * CSTR + ki], -IEPS, lmq_s[jj * 8 + i]);
    }
    const float lmq_k = lmq_s[ki];
    const float lmr_m = lmr_s[ki];

    for (int it = 0; it < NITER; ++it) {
        float mx = -1e30f;
        #pragma unroll
        for (int i = 0; i < 8; ++i) mx = fmaxf(mx, rowV[i] + lb_s[jj * 8 + i]);
        mx = fmaxf(mx, __shfl_xor(mx, 1));
        mx = fmaxf(mx, __shfl_xor(mx, 2));
        mx = fmaxf(mx, __shfl_xor(mx, 4));
        float s = 0.0f;
        #pragma unroll
        for (int i = 0; i < 8; ++i) s += __expf(rowV[i] + lb_s[jj * 8 + i] - mx);
        s += __shfl_xor(s, 1);
        s += __shfl_xor(s, 2);
        s += __shfl_xor(s, 4);
        if (jj == 0) la_s[ki] = -(lmq_k + mx + __logf(s));
        __syncthreads();

        mx = -1e30f;
        #pragma unroll
        for (int i = 0; i < 8; ++i) mx = fmaxf(mx, colV[i] + la_s[jj * 8 + i]);
        mx = fmaxf(mx, __shfl_xor(mx, 1));
        mx = fmaxf(mx, __shfl_xor(mx, 2));
        mx = fmaxf(mx, __shfl_xor(mx, 4));
        float s2 = 0.0f;
        #pragma unroll
        for (int i = 0; i < 8; ++i) s2 += __expf(colV[i] + la_s[jj * 8 + i] - mx);
        s2 += __shfl_xor(s2, 1);
        s2 += __shfl_xor(s2, 2);
        s2 += __shfl_xor(s2, 4);
        if (jj == 0) lb_s[ki] = -(lmr_m + mx + __logf(s2));
        __syncthreads();
    }

    {
        const float base = lmq_k + la_s[ki];
        #pragma unroll
        for (int i = 0; i < 8; ++i) {
            const int m2 = jj * 8 + i;
            Ts[ki * CSTR + m2] = __expf(rowV[i] + lb_s[m2] + base);
        }
    }
    __syncthreads();

    for (int pi = 0; pi < MITER; ++pi) {
        float vv[8], rs = 0.0f;
        #pragma unroll
        for (int i = 0; i < 8; ++i) {
            float v = Ts[ki * CSTR + jj * 8 + i];
            v = v * v; vv[i] = v; rs += v;
        }
        rs += __shfl_xor(rs, 1); rs += __shfl_xor(rs, 2); rs += __shfl_xor(rs, 4);
        float inv = 1.0f / (rs + 1e-8f);
        #pragma unroll
        for (int i = 0; i < 8; ++i) Ts[ki * CSTR + jj * 8 + i] = vv[i] * inv;
        __syncthreads();

        float cs = 0.0f;
        #pragma unroll
        for (int i = 0; i < 8; ++i) { float v = Ts[(jj * 8 + i) * CSTR + ki]; vv[i] = v; cs += v; }
        cs += __shfl_xor(cs, 1); cs += __shfl_xor(cs, 2); cs += __shfl_xor(cs, 4);
        inv = 1.0f / (cs + 1e-8f);
        #pragma unroll
        for (int i = 0; i < 8; ++i) Ts[(jj * 8 + i) * CSTR + ki] = vv[i] * inv;
        __syncthreads();
    }

    {
        float part = 0.0f;
        float tq[8];
        #pragma unroll
        for (int i = 0; i < 8; ++i) {
            const int m2 = jj * 8 + i;
            float tv = Ts[ki * CSTR + m2];
            tq[i] = tv;
            part = fmaf(tv, Cs[ki * CSTR + m2], part);
        }
        float* outT = out + 2048 + (size_t)b * 4096 + ki * 64 + jj * 8;
        ((float4*)outT)[0] = make_float4(tq[0], tq[1], tq[2], tq[3]);
        ((float4*)outT)[1] = make_float4(tq[4], tq[5], tq[6], tq[7]);
        #pragma unroll
        for (int off = 1; off < 64; off <<= 1) part += __shfl_xor(part, off);
        if (ln == 0) red_s[wv] = part;
    }
    __syncthreads();
    if (t == 0) {
        float c = 0.0f;
        #pragma unroll
        for (int w = 0; w < 8; ++w) c += red_s[w];
        out[2048 + (size_t)2 * 2048 * 4096 + b] = c;
        out[b] = 1.0f / (1.0f + __expf(c));
    }
}

extern "C" void kernel_launch(void* const* d_in, const int* in_sizes, int n_in,
                              void* d_out, int out_size, void* d_ws, size_t ws_size,
                              hipStream_t stream) {
    const float* sq = (const float*)d_in[0];
    const float* sr = (const float*)d_in[1];
    const float* mq = (const float*)d_in[2];
    const float* mr = (const float*)d_in[3];
    const float* W1 = (const float*)d_in[4];
    const float* b1 = (const float*)d_in[5];
    const float* W2 = (const float*)d_in[6];
    const float* b2 = (const float*)d_in[7];

    bf16_t* wf = (bf16_t*)d_ws;   // 131072 bf16 = 256 KB

    convert_w_frag<<<512, 256, 0, stream>>>(W1, W2, wf);
    mlp_cdist<<<256, 512, 0, stream>>>(sq, sr, b1, b2, wf, (float*)d_out);
    sinkhorn_from_C<<<NB, 512, 0, stream>>>(mq, mr, (float*)d_out);
}